// Round 5
// baseline (7690.343 us; speedup 1.0000x reference)
//
#include <hip/hip_runtime.h>

// ---------------- problem constants ----------------
#define S_LEN 512
#define HID   512
#define IN_D  64
#define GATES 2048            // 4*HID
#define K0    576             // IN_D + HID
#define K1    1024            // HID + HID
#define KP0   578             // padded LDS stride (dwords % 32 == 1 -> conflict-free B reads)
#define KP1   1026
#define CLUSTERS 4
#define WGS   64              // workgroups per cluster
#define BPC   16              // batch rows per cluster
#define NBLOCKS 256
#define NTHREADS 256

typedef _Float16 f16;
typedef _Float16 f16x8 __attribute__((ext_vector_type(8)));
typedef float    f32x4 __attribute__((ext_vector_type(4)));

// ---------------- LDS layout (dynamic) ----------------
#define LDS_W0_OFF  0
#define LDS_W1_OFF  (32 * KP0 * 2)                    // 36992
#define LDS_STG_OFF (LDS_W1_OFF + 32 * KP1 * 2)      // 102656
#define LDS_TOTAL   (LDS_STG_OFF + 4 * 16 * 17 * 4)  // 107008 bytes

// ---------------- workspace layout ----------------
// [0 .. 64K): flags. cluster c: f0 (128 u32) at c*8192, f1 at c*8192+4096.
// [64K .. ): versioned h slots: (cl*2+layer)*Wn + (t & wmask), 32 KB each
//            (hi plane 16 KB [16 rows][512 cols] f16, then lo plane 16 KB)
#define WS_FLAG_BYTES 65536
#define SLOT_BYTES    32768

#define RELEASE_DRAIN() asm volatile("s_waitcnt vmcnt(0) lgkmcnt(0)" ::: "memory")

__device__ __forceinline__ float sigf(float v) {
  v = fminf(fmaxf(v, -30.f), 30.f);
  return 1.f / (1.f + __expf(-v));
}
__device__ __forceinline__ float tanh_f(float v) {
  v = fminf(fmaxf(v, -15.f), 15.f);
  float e = __expf(2.f * v);
  return (e - 1.f) / (e + 1.f);
}

// wait until all 128 u32 flags (viewed as 64 u64) are >= tgt
__device__ __forceinline__ void wait_ge(const unsigned long long* f, unsigned int tgt, int lane) {
  for (;;) {
    unsigned long long v = __hip_atomic_load(f + lane, __ATOMIC_RELAXED, __HIP_MEMORY_SCOPE_AGENT);
    bool ok = ((unsigned int)v >= tgt) && ((unsigned int)(v >> 32) >= tgt);
    if (__ballot(ok) == ~0ULL) break;
    __builtin_amdgcn_s_sleep(1);
  }
  asm volatile("" ::: "memory");   // compiler acquire: keep h loads after the poll
}

extern "C" __global__ void __launch_bounds__(NTHREADS, 1)
lstm_persist(const float* __restrict__ x,  const float* __restrict__ W0,
             const float* __restrict__ b0, const float* __restrict__ W1,
             const float* __restrict__ b1, const float* __restrict__ Wfc,
             const float* __restrict__ bfc, float* __restrict__ out,
             unsigned char* __restrict__ ws, int Wn, int wmask, int fimask, int slack)
{
  extern __shared__ char lds[];
  f16*   w0l     = (f16*)(lds + LDS_W0_OFF);
  f16*   w1l     = (f16*)(lds + LDS_W1_OFF);
  float* stgbase = (float*)(lds + LDS_STG_OFF);

  const int tid   = threadIdx.x;
  const int wg    = blockIdx.x & (WGS - 1);
  const int cl    = blockIdx.x / WGS;
  const int wave  = tid >> 6;
  const int lane  = tid & 63;
  const int hbase = wg * 8;

  // ---- one-time: gather + transpose this WG's weight columns into LDS (fp16) ----
  {
    const int nl = tid & 31;
    const int wtile = nl >> 4, wi = nl & 15, g = wi >> 2, jj = wi & 3;
    const int col = g * HID + hbase + wtile * 4 + jj;
    for (int k = tid >> 5; k < K0; k += 8)
      w0l[nl * KP0 + k] = (f16)W0[(size_t)k * GATES + col];
    for (int k = tid >> 5; k < K1; k += 8)
      w1l[nl * KP1 + k] = (f16)W1[(size_t)k * GATES + col];
  }
  __syncthreads();   // last block-wide sync; waves run independently below

  // ---- per-wave constants ----
  const int layer = wave >> 1;
  const int tile  = wave & 1;
  const int fm  = lane & 15;
  const int q8  = (lane >> 4) * 8;

  // ---- ROUND-5 DELTA: hoist this wave's weight fragments LDS -> VGPRs.
  // Reads the exact addresses the inner loop previously read every step.
  // w0l/w1l are never written after staging, so this is protocol-neutral.
  f16x8 wx[2];    // L0 only: x-part k-slices
  f16x8 wh[16];   // L0: h-part; L1: h0-part
  f16x8 wr[16];   // L1 only: h1-part
  if (layer == 0) {
    const f16* base = w0l + (size_t)(tile * 16 + fm) * KP0;
    #pragma unroll
    for (int kb = 0; kb < 2; ++kb)
      wx[kb] = *(const f16x8*)(base + kb * 32 + q8);
    #pragma unroll
    for (int kb = 0; kb < 16; ++kb)
      wh[kb] = *(const f16x8*)(base + IN_D + kb * 32 + q8);
  } else {
    const f16* base = w1l + (size_t)(tile * 16 + fm) * KP1;
    #pragma unroll
    for (int kb = 0; kb < 16; ++kb)
      wh[kb] = *(const f16x8*)(base + kb * 32 + q8);
    #pragma unroll
    for (int kb = 0; kb < 16; ++kb)
      wr[kb] = *(const f16x8*)(base + HID + kb * 32 + q8);
  }

  const int cb    = hbase + tile * 4;
  const int wid   = wg * 2 + tile;            // producer-wave flag index (0..127)
  const int erow  = lane >> 2;
  const int ehc   = lane & 3;
  const int hcol  = cb + ehc;
  const float* bsrc = layer ? b1 : b0;
  const float bg0 = bsrc[0 * HID + hcol];
  const float bg1 = bsrc[1 * HID + hcol];
  const float bg2 = bsrc[2 * HID + hcol];
  const float bg3 = bsrc[3 * HID + hcol];
  float cstate = 0.f;
  float* stg = stgbase + wave * (16 * 17);

  const int brow = cl * BPC + fm;

  unsigned char* hby = ws + WS_FLAG_BYTES;
  unsigned int*  f0s = (unsigned int*)(ws + (size_t)cl * 8192);
  unsigned int*  f1s = (unsigned int*)(ws + (size_t)cl * 8192 + 4096);
  const unsigned long long* f0c = (const unsigned long long*)f0s;
  const unsigned long long* f1c = (const unsigned long long*)f1s;

  auto slotp = [&](int lyr, int t, int hl) -> f16* {
    return (f16*)(hby + ((size_t)((cl * 2 + lyr) * Wn + (t & wmask)) << 15) + (hl << 14));
  };

  // epilogue: acc -> gates -> (h, cstate) -> versioned slot store
  auto do_epilogue = [&](f32x4 acc, int t) {
    #pragma unroll
    for (int r = 0; r < 4; ++r)
      stg[((lane >> 4) * 4 + r) * 17 + fm] = acc[r];
    float iv = stg[erow * 17 + 0 + ehc]  + bg0;
    float fv = stg[erow * 17 + 4 + ehc]  + bg1;
    float gv = stg[erow * 17 + 8 + ehc]  + bg2;
    float ov = stg[erow * 17 + 12 + ehc] + bg3;
    float ig = sigf(iv), fg = sigf(fv), gg = tanh_f(gv), og = sigf(ov);
    cstate = fg * cstate + ig * gg;
    float h = og * tanh_f(cstate);

    const int src0 = fm * 4 + ((lane >> 4) & 1) * 2;
    float ha = __shfl(h, src0, 64);
    float hb = __shfl(h, src0 + 1, 64);
    if (lane < 32) {
      const int wrow = lane & 15, wpair = lane >> 4;
      f16* phi = slotp(layer, t, 0);
      f16* plo = slotp(layer, t, 1);
      f16 hah = (f16)ha; f16 hal = (f16)(ha - (float)hah);
      f16 hbh = (f16)hb; f16 hbl = (f16)(hb - (float)hbh);
      unsigned int hw = (unsigned int)__builtin_bit_cast(unsigned short, hah) |
                        ((unsigned int)__builtin_bit_cast(unsigned short, hbh) << 16);
      unsigned int lw = (unsigned int)__builtin_bit_cast(unsigned short, hal) |
                        ((unsigned int)__builtin_bit_cast(unsigned short, hbl) << 16);
      const int coff = wrow * HID + cb + wpair * 2;
      __hip_atomic_store((unsigned int*)(phi + coff), hw, __ATOMIC_RELAXED, __HIP_MEMORY_SCOPE_AGENT);
      __hip_atomic_store((unsigned int*)(plo + coff), lw, __ATOMIC_RELAXED, __HIP_MEMORY_SCOPE_AGENT);
    }
    RELEASE_DRAIN();   // h stores ack'd at coherence point before flag store
  };

  if (layer == 0) {
    for (int t = 0; t < S_LEN; ++t) {
      if (t && (t & fimask) == 0)
        __builtin_amdgcn_fence(__ATOMIC_ACQUIRE, "agent");  // slot-reuse invalidate (every W/2)
      f32x4 acc = {0.f, 0.f, 0.f, 0.f};
      // x part first: independent of the recurrence
      const float* xr = x + ((size_t)brow * S_LEN + t) * IN_D + q8;
      #pragma unroll
      for (int kb = 0; kb < 2; ++kb) {
        f32x4 xa = *(const f32x4*)(xr + kb * 32);
        f32x4 xb = *(const f32x4*)(xr + kb * 32 + 4);
        f16x8 a = { (f16)xa[0], (f16)xa[1], (f16)xa[2], (f16)xa[3],
                    (f16)xb[0], (f16)xb[1], (f16)xb[2], (f16)xb[3] };
        acc = __builtin_amdgcn_mfma_f32_16x16x32_f16(a, wx[kb], acc, 0, 0, 0);
      }
      if (t) {
        wait_ge(f0c, (unsigned)t, lane);                    // h0(t-1) ready
        if (t > slack) wait_ge(f1c, (unsigned)(t - slack), lane);  // window back-pressure
        const f16* hpi = slotp(0, t - 1, 0);
        const f16* hpl = slotp(0, t - 1, 1);
        #pragma unroll 4
        for (int kb = 0; kb < 16; ++kb) {
          const int k = kb * 32 + q8;
          f16x8 ah = *(const f16x8*)(hpi + fm * HID + k);
          f16x8 al = *(const f16x8*)(hpl + fm * HID + k);
          acc = __builtin_amdgcn_mfma_f32_16x16x32_f16(ah, wh[kb], acc, 0, 0, 0);
          acc = __builtin_amdgcn_mfma_f32_16x16x32_f16(al, wh[kb], acc, 0, 0, 0);
        }
      }
      do_epilogue(acc, t);
      if (lane == 0)
        __hip_atomic_store(f0s + wid, (unsigned)(t + 1), __ATOMIC_RELAXED, __HIP_MEMORY_SCOPE_AGENT);
    }
  } else {
    for (int t = 0; t < S_LEN; ++t) {
      if (t && (t & fimask) == 0)
        __builtin_amdgcn_fence(__ATOMIC_ACQUIRE, "agent");
      f32x4 acc = {0.f, 0.f, 0.f, 0.f};
      wait_ge(f0c, (unsigned)(t + 1), lane);                // h0(t) ready
      {
        const f16* h0i = slotp(0, t, 0);
        const f16* h0l = slotp(0, t, 1);
        #pragma unroll 4
        for (int kb = 0; kb < 16; ++kb) {
          const int k = kb * 32 + q8;
          f16x8 ah = *(const f16x8*)(h0i + fm * HID + k);
          f16x8 al = *(const f16x8*)(h0l + fm * HID + k);
          acc = __builtin_amdgcn_mfma_f32_16x16x32_f16(ah, wh[kb], acc, 0, 0, 0);
          acc = __builtin_amdgcn_mfma_f32_16x16x32_f16(al, wh[kb], acc, 0, 0, 0);
        }
      }
      if (t) {
        wait_ge(f1c, (unsigned)t, lane);                    // h1(t-1) ready (peers)
        const f16* h1i = slotp(1, t - 1, 0);
        const f16* h1l = slotp(1, t - 1, 1);
        #pragma unroll 4
        for (int kb = 0; kb < 16; ++kb) {
          const int k = kb * 32 + q8;
          f16x8 ah = *(const f16x8*)(h1i + fm * HID + k);
          f16x8 al = *(const f16x8*)(h1l + fm * HID + k);
          acc = __builtin_amdgcn_mfma_f32_16x16x32_f16(ah, wr[kb], acc, 0, 0, 0);
          acc = __builtin_amdgcn_mfma_f32_16x16x32_f16(al, wr[kb], acc, 0, 0, 0);
        }
      }
      do_epilogue(acc, t);
      if (lane == 0)
        __hip_atomic_store(f1s + wid, (unsigned)(t + 1), __ATOMIC_RELAXED, __HIP_MEMORY_SCOPE_AGENT);
    }
  }

  // ---- output head: WG0 of each cluster reads h1(511) ----
  if (wg == 0) {
    wait_ge(f1c, (unsigned)S_LEN, lane);
    __builtin_amdgcn_fence(__ATOMIC_ACQUIRE, "agent");
    const f16* h1i = slotp(1, S_LEN - 1, 0);
    const f16* h1l = slotp(1, S_LEN - 1, 1);
    #pragma unroll
    for (int rr = 0; rr < 4; ++rr) {
      const int r = wave * 4 + rr;
      float sum = 0.f;
      for (int k = lane; k < HID; k += 64) {
        float hv = (float)h1i[r * HID + k] + (float)h1l[r * HID + k];
        sum += hv * Wfc[k];
      }
      #pragma unroll
      for (int off = 32; off > 0; off >>= 1)
        sum += __shfl_down(sum, off, 64);
      if (lane == 0) out[cl * BPC + r] = sum + bfc[0];
    }
  }
}

extern "C" void kernel_launch(void* const* d_in, const int* in_sizes, int n_in,
                              void* d_out, int out_size, void* d_ws, size_t ws_size,
                              hipStream_t stream) {
  const float* x   = (const float*)d_in[0];
  const float* W0  = (const float*)d_in[1];
  const float* b0  = (const float*)d_in[2];
  const float* W1  = (const float*)d_in[3];
  const float* b1  = (const float*)d_in[4];
  const float* Wfc = (const float*)d_in[5];
  const float* bfc = (const float*)d_in[6];
  float* out = (float*)d_out;
  unsigned char* ws = (unsigned char*)d_ws;

  (void)in_sizes; (void)n_in; (void)out_size;

  // window size from available workspace (cap 64 slots = 16.8 MB)
  int Wn = 2;
  while (Wn < 64 &&
         WS_FLAG_BYTES + (size_t)(Wn * 2) * (CLUSTERS * 2 * SLOT_BYTES) <= ws_size)
    Wn *= 2;
  int wmask  = Wn - 1;
  int fimask = (Wn >= 4) ? (Wn / 2 - 1) : 0;  // acquire-fence every Wn/2 steps
  int slack  = Wn - 2;

  hipFuncSetAttribute((const void*)lstm_persist,
                      hipFuncAttributeMaxDynamicSharedMemorySize, LDS_TOTAL);

  // zero only the flag region each call (h slots are written before read)
  hipMemsetAsync(ws, 0, WS_FLAG_BYTES, stream);

  void* args[] = { &x, &W0, &b0, &W1, &b1, &Wfc, &bfc, &out, &ws,
                   &Wn, &wmask, &fimask, &slack };
  hipLaunchCooperativeKernel((void*)lstm_persist, dim3(NBLOCKS), dim3(NTHREADS),
                             args, LDS_TOTAL, stream);
}

// Round 8
// 6344.246 us; speedup vs baseline: 1.2122x; 1.2122x over previous
//
#include <hip/hip_runtime.h>

// ---------------- problem constants ----------------
#define S_LEN 512
#define HID   512
#define IN_D  64
#define GATES 2048            // 4*HID
#define K0    576             // IN_D + HID
#define K1    1024            // HID + HID
#define KP0   578             // padded LDS stride (dwords % 32 == 1 -> conflict-free B reads)
#define KP1   1026
#define CLUSTERS 4
#define WGS   64              // workgroups per cluster
#define BPC   16              // batch rows per cluster
#define NBLOCKS 256
#define NTHREADS 256
#define NPROD 128u            // producer waves per layer per cluster (64 WGs x 2 waves)

typedef _Float16 f16;
typedef _Float16 f16x8 __attribute__((ext_vector_type(8)));
typedef float    f32x4 __attribute__((ext_vector_type(4)));

// ---------------- LDS layout (dynamic) ----------------
#define LDS_W0_OFF  0
#define LDS_W1_OFF  (32 * KP0 * 2)                    // 36992
#define LDS_STG_OFF (LDS_W1_OFF + 32 * KP1 * 2)      // 102656
#define LDS_TOTAL   (LDS_STG_OFF + 4 * 16 * 17 * 4)  // 107008 bytes

// ---------------- workspace layout ----------------
// [0 .. 64K): per-cluster step counters (round-7 delta — replaces flag arrays).
//   cluster c: f0cnt = u32[512] at c*8192, f1cnt = u32[512] at c*8192 + 2048.
//   f0cnt[t] counts L0 producer-waves that finished step t (data drained first);
//   "all h0(t) ready" <=> f0cnt[t] == 128. One counter word per step -> no
//   reuse/reset; zeroed by the launch-time memset.
// [64K .. ): versioned h slots (UNCHANGED from round 0):
//   (cl*2+layer)*Wn + (t & wmask), 32 KB each (hi plane 16 KB, lo plane 16 KB)
// ROUND 8 = byte-identical resubmission of round 7 (infra "container failed
// twice" with no pytest output; source re-audited compile-clean, runtime
// bounded by poll budget -> resubmit as the control).
#define WS_FLAG_BYTES 65536
#define SLOT_BYTES    32768

#define RELEASE_DRAIN() asm volatile("s_waitcnt vmcnt(0) lgkmcnt(0)" ::: "memory")

__device__ __forceinline__ float sigf(float v) {
  v = fminf(fmaxf(v, -30.f), 30.f);
  return 1.f / (1.f + __expf(-v));
}
__device__ __forceinline__ float tanh_f(float v) {
  v = fminf(fmaxf(v, -15.f), 15.f);
  float e = __expf(2.f * v);
  return (e - 1.f) / (e + 1.f);
}

// single-word count poll. Wave-uniform address -> one broadcast load per wave
// per iteration (vs round 0's 64-lane x 8-line gather).
// budget bail-out: protocol failure -> finishes fast with wrong numbers (loud).
__device__ __forceinline__ void wait_cnt(const unsigned* p, unsigned need, int& budget) {
  for (;;) {
    unsigned v = __hip_atomic_load(p, __ATOMIC_RELAXED, __HIP_MEMORY_SCOPE_AGENT);
    if (v >= need) break;
    if (--budget < 0) break;
    __builtin_amdgcn_s_sleep(1);
  }
  asm volatile("" ::: "memory");   // compiler acquire: keep h loads after the poll
}

extern "C" __global__ void __launch_bounds__(NTHREADS, 1)
lstm_persist(const float* __restrict__ x,  const float* __restrict__ W0,
             const float* __restrict__ b0, const float* __restrict__ W1,
             const float* __restrict__ b1, const float* __restrict__ Wfc,
             const float* __restrict__ bfc, float* __restrict__ out,
             unsigned char* __restrict__ ws, int Wn, int wmask, int fimask, int slack)
{
  extern __shared__ char lds[];
  f16*   w0l     = (f16*)(lds + LDS_W0_OFF);
  f16*   w1l     = (f16*)(lds + LDS_W1_OFF);
  float* stgbase = (float*)(lds + LDS_STG_OFF);

  const int tid   = threadIdx.x;
  const int wg    = blockIdx.x & (WGS - 1);
  const int cl    = blockIdx.x / WGS;
  const int wave  = tid >> 6;
  const int lane  = tid & 63;
  const int hbase = wg * 8;

  // ---- one-time: gather + transpose this WG's weight columns into LDS (fp16) ----
  {
    const int nl = tid & 31;
    const int wtile = nl >> 4, wi = nl & 15, g = wi >> 2, jj = wi & 3;
    const int col = g * HID + hbase + wtile * 4 + jj;
    for (int k = tid >> 5; k < K0; k += 8)
      w0l[nl * KP0 + k] = (f16)W0[(size_t)k * GATES + col];
    for (int k = tid >> 5; k < K1; k += 8)
      w1l[nl * KP1 + k] = (f16)W1[(size_t)k * GATES + col];
  }
  __syncthreads();   // last block-wide sync; waves run independently below

  // ---- per-wave constants ----
  const int layer = wave >> 1;
  const int tile  = wave & 1;
  const int cb    = hbase + tile * 4;
  const int erow  = lane >> 2;
  const int ehc   = lane & 3;
  const int hcol  = cb + ehc;
  const float* bsrc = layer ? b1 : b0;
  const float bg0 = bsrc[0 * HID + hcol];
  const float bg1 = bsrc[1 * HID + hcol];
  const float bg2 = bsrc[2 * HID + hcol];
  const float bg3 = bsrc[3 * HID + hcol];
  float cstate = 0.f;
  float* stg = stgbase + wave * (16 * 17);

  const int fm  = lane & 15;
  const int q8  = (lane >> 4) * 8;
  const int brow = cl * BPC + fm;

  unsigned char* hby = ws + WS_FLAG_BYTES;
  unsigned int* f0cnt = (unsigned int*)(ws + (size_t)cl * 8192);
  unsigned int* f1cnt = (unsigned int*)(ws + (size_t)cl * 8192 + 2048);
  int budget = 1 << 20;

  auto slotp = [&](int lyr, int t, int hl) -> f16* {
    return (f16*)(hby + ((size_t)((cl * 2 + lyr) * Wn + (t & wmask)) << 15) + (hl << 14));
  };

  // epilogue: acc -> gates -> (h, cstate) -> versioned slot store
  auto do_epilogue = [&](f32x4 acc, int t) {
    #pragma unroll
    for (int r = 0; r < 4; ++r)
      stg[((lane >> 4) * 4 + r) * 17 + fm] = acc[r];
    float iv = stg[erow * 17 + 0 + ehc]  + bg0;
    float fv = stg[erow * 17 + 4 + ehc]  + bg1;
    float gv = stg[erow * 17 + 8 + ehc]  + bg2;
    float ov = stg[erow * 17 + 12 + ehc] + bg3;
    float ig = sigf(iv), fg = sigf(fv), gg = tanh_f(gv), og = sigf(ov);
    cstate = fg * cstate + ig * gg;
    float h = og * tanh_f(cstate);

    const int src0 = fm * 4 + ((lane >> 4) & 1) * 2;
    float ha = __shfl(h, src0, 64);
    float hb = __shfl(h, src0 + 1, 64);
    if (lane < 32) {
      const int wrow = lane & 15, wpair = lane >> 4;
      f16* phi = slotp(layer, t, 0);
      f16* plo = slotp(layer, t, 1);
      f16 hah = (f16)ha; f16 hal = (f16)(ha - (float)hah);
      f16 hbh = (f16)hb; f16 hbl = (f16)(hb - (float)hbh);
      unsigned int hw = (unsigned int)__builtin_bit_cast(unsigned short, hah) |
                        ((unsigned int)__builtin_bit_cast(unsigned short, hbh) << 16);
      unsigned int lw = (unsigned int)__builtin_bit_cast(unsigned short, hal) |
                        ((unsigned int)__builtin_bit_cast(unsigned short, hbl) << 16);
      const int coff = wrow * HID + cb + wpair * 2;
      __hip_atomic_store((unsigned int*)(phi + coff), hw, __ATOMIC_RELAXED, __HIP_MEMORY_SCOPE_AGENT);
      __hip_atomic_store((unsigned int*)(plo + coff), lw, __ATOMIC_RELAXED, __HIP_MEMORY_SCOPE_AGENT);
    }
    RELEASE_DRAIN();   // h stores ack'd at coherence point before the count bump
  };

  if (layer == 0) {
    for (int t = 0; t < S_LEN; ++t) {
      if (t && (t & fimask) == 0)
        __builtin_amdgcn_fence(__ATOMIC_ACQUIRE, "agent");  // slot-reuse invalidate (every W/2)
      f32x4 acc = {0.f, 0.f, 0.f, 0.f};
      // x part first: independent of the recurrence
      const float* xr = x + ((size_t)brow * S_LEN + t) * IN_D + q8;
      #pragma unroll
      for (int kb = 0; kb < 2; ++kb) {
        f32x4 xa = *(const f32x4*)(xr + kb * 32);
        f32x4 xb = *(const f32x4*)(xr + kb * 32 + 4);
        f16x8 a = { (f16)xa[0], (f16)xa[1], (f16)xa[2], (f16)xa[3],
                    (f16)xb[0], (f16)xb[1], (f16)xb[2], (f16)xb[3] };
        f16x8 bf = *(const f16x8*)(w0l + (tile * 16 + fm) * KP0 + kb * 32 + q8);
        acc = __builtin_amdgcn_mfma_f32_16x16x32_f16(a, bf, acc, 0, 0, 0);
      }
      if (t) {
        wait_cnt(f0cnt + (t - 1), NPROD, budget);               // h0(t-1) ready
        if (t > slack) wait_cnt(f1cnt + (t - slack - 1), NPROD, budget);  // window back-pressure
        const f16* hpi = slotp(0, t - 1, 0);
        const f16* hpl = slotp(0, t - 1, 1);
        #pragma unroll 4
        for (int kb = 0; kb < 16; ++kb) {
          const int k = kb * 32 + q8;
          f16x8 bf = *(const f16x8*)(w0l + (tile * 16 + fm) * KP0 + IN_D + k);
          f16x8 ah = *(const f16x8*)(hpi + fm * HID + k);
          f16x8 al = *(const f16x8*)(hpl + fm * HID + k);
          acc = __builtin_amdgcn_mfma_f32_16x16x32_f16(ah, bf, acc, 0, 0, 0);
          acc = __builtin_amdgcn_mfma_f32_16x16x32_f16(al, bf, acc, 0, 0, 0);
        }
      }
      do_epilogue(acc, t);
      if (lane == 0) atomicAdd(f0cnt + t, 1u);                  // device-scope (G12)
    }
  } else {
    for (int t = 0; t < S_LEN; ++t) {
      if (t && (t & fimask) == 0)
        __builtin_amdgcn_fence(__ATOMIC_ACQUIRE, "agent");
      f32x4 acc = {0.f, 0.f, 0.f, 0.f};
      wait_cnt(f0cnt + t, NPROD, budget);                       // h0(t) ready
      {
        const f16* h0i = slotp(0, t, 0);
        const f16* h0l = slotp(0, t, 1);
        #pragma unroll 4
        for (int kb = 0; kb < 16; ++kb) {
          const int k = kb * 32 + q8;
          f16x8 bf = *(const f16x8*)(w1l + (tile * 16 + fm) * KP1 + k);
          f16x8 ah = *(const f16x8*)(h0i + fm * HID + k);
          f16x8 al = *(const f16x8*)(h0l + fm * HID + k);
          acc = __builtin_amdgcn_mfma_f32_16x16x32_f16(ah, bf, acc, 0, 0, 0);
          acc = __builtin_amdgcn_mfma_f32_16x16x32_f16(al, bf, acc, 0, 0, 0);
        }
      }
      if (t) {
        wait_cnt(f1cnt + (t - 1), NPROD, budget);               // h1(t-1) ready (peers)
        const f16* h1i = slotp(1, t - 1, 0);
        const f16* h1l = slotp(1, t - 1, 1);
        #pragma unroll 4
        for (int kb = 0; kb < 16; ++kb) {
          const int k = kb * 32 + q8;
          f16x8 bf = *(const f16x8*)(w1l + (tile * 16 + fm) * KP1 + HID + k);
          f16x8 ah = *(const f16x8*)(h1i + fm * HID + k);
          f16x8 al = *(const f16x8*)(h1l + fm * HID + k);
          acc = __builtin_amdgcn_mfma_f32_16x16x32_f16(ah, bf, acc, 0, 0, 0);
          acc = __builtin_amdgcn_mfma_f32_16x16x32_f16(al, bf, acc, 0, 0, 0);
        }
      }
      do_epilogue(acc, t);
      if (lane == 0) atomicAdd(f1cnt + t, 1u);
    }
  }

  // ---- output head: WG0 of each cluster reads h1(511) ----
  if (wg == 0) {
    wait_cnt(f1cnt + (S_LEN - 1), NPROD, budget);
    __builtin_amdgcn_fence(__ATOMIC_ACQUIRE, "agent");
    const f16* h1i = slotp(1, S_LEN - 1, 0);
    const f16* h1l = slotp(1, S_LEN - 1, 1);
    #pragma unroll
    for (int rr = 0; rr < 4; ++rr) {
      const int r = wave * 4 + rr;
      float sum = 0.f;
      for (int k = lane; k < HID; k += 64) {
        float hv = (float)h1i[r * HID + k] + (float)h1l[r * HID + k];
        sum += hv * Wfc[k];
      }
      #pragma unroll
      for (int off = 32; off > 0; off >>= 1)
        sum += __shfl_down(sum, off, 64);
      if (lane == 0) out[cl * BPC + r] = sum + bfc[0];
    }
  }
}

extern "C" void kernel_launch(void* const* d_in, const int* in_sizes, int n_in,
                              void* d_out, int out_size, void* d_ws, size_t ws_size,
                              hipStream_t stream) {
  const float* x   = (const float*)d_in[0];
  const float* W0  = (const float*)d_in[1];
  const float* b0  = (const float*)d_in[2];
  const float* W1  = (const float*)d_in[3];
  const float* b1  = (const float*)d_in[4];
  const float* Wfc = (const float*)d_in[5];
  const float* bfc = (const float*)d_in[6];
  float* out = (float*)d_out;
  unsigned char* ws = (unsigned char*)d_ws;

  (void)in_sizes; (void)n_in; (void)out_size;

  // window size from available workspace (cap 64 slots = 16.8 MB)
  int Wn = 2;
  while (Wn < 64 &&
         WS_FLAG_BYTES + (size_t)(Wn * 2) * (CLUSTERS * 2 * SLOT_BYTES) <= ws_size)
    Wn *= 2;
  int wmask  = Wn - 1;
  int fimask = (Wn >= 4) ? (Wn / 2 - 1) : 0;  // acquire-fence every Wn/2 steps
  int slack  = Wn - 2;

  hipFuncSetAttribute((const void*)lstm_persist,
                      hipFuncAttributeMaxDynamicSharedMemorySize, LDS_TOTAL);

  // zero the flag/counter region each call (h slots are written before read)
  hipMemsetAsync(ws, 0, WS_FLAG_BYTES, stream);

  void* args[] = { &x, &W0, &b0, &W1, &b1, &Wfc, &bfc, &out, &ws,
                   &Wn, &wmask, &fimask, &slack };
  hipLaunchCooperativeKernel((void*)lstm_persist, dim3(NBLOCKS), dim3(NTHREADS),
                             args, LDS_TOTAL, stream);
}

// Round 9
// 5184.919 us; speedup vs baseline: 1.4832x; 1.2236x over previous
//
#include <hip/hip_runtime.h>

// ---------------- problem constants ----------------
#define S_LEN 512
#define HID   512
#define IN_D  64
#define GATES 2048            // 4*HID
#define K0    576             // IN_D + HID
#define K1    1024            // HID + HID
#define KP0   578             // padded LDS stride (dwords % 32 == 1 -> conflict-free B reads)
#define KP1   1026
#define CLUSTERS 4
#define WGS   64              // workgroups per cluster
#define BPC   16              // batch rows per cluster
#define NBLOCKS 256
#define NTHREADS 256
#define NPROD 128u            // producer waves per layer per cluster (64 WGs x 2 waves)

typedef _Float16 f16;
typedef _Float16 f16x8 __attribute__((ext_vector_type(8)));
typedef float    f32x4 __attribute__((ext_vector_type(4)));

// ---------------- LDS layout (dynamic) ----------------
#define LDS_W0_OFF  0
#define LDS_W1_OFF  (32 * KP0 * 2)                    // 36992
#define LDS_STG_OFF (LDS_W1_OFF + 32 * KP1 * 2)      // 102656
#define LDS_TOTAL   (LDS_STG_OFF + 4 * 16 * 17 * 4)  // 107008 bytes

// ---------------- workspace layout ----------------
// [0 .. 64K): per-cluster step counters.
//   cluster c: f0cnt = u32[512] at c*8192, f1cnt = u32[512] at c*8192 + 2048.
//   f0cnt[t] counts L0 producer-waves that finished step t (data drained first);
//   "all h0(t) ready" <=> f0cnt[t] == 128. One counter word per step.
// [64K .. ): versioned h slots:
//   (cl*2+layer)*Wn + (t & wmask), 32 KB each (hi plane 16 KB, lo plane 16 KB)
// ROUND 9 DELTA (compute-local only, protocol untouched):
//   (a) batch all 32 h-tile loads into registers before the MFMA loop
//       (one latency exposure instead of four unroll-4 groups);
//   (b) split accumulation into independent hi/lo chains (depth 32 -> 16).
#define WS_FLAG_BYTES 65536
#define SLOT_BYTES    32768

#define RELEASE_DRAIN() asm volatile("s_waitcnt vmcnt(0) lgkmcnt(0)" ::: "memory")
#define MFMA(a,b,c) __builtin_amdgcn_mfma_f32_16x16x32_f16((a),(b),(c),0,0,0)

__device__ __forceinline__ float sigf(float v) {
  v = fminf(fmaxf(v, -30.f), 30.f);
  return 1.f / (1.f + __expf(-v));
}
__device__ __forceinline__ float tanh_f(float v) {
  v = fminf(fmaxf(v, -15.f), 15.f);
  float e = __expf(2.f * v);
  return (e - 1.f) / (e + 1.f);
}

// single-word count poll. Wave-uniform address -> one broadcast load per wave.
// budget bail-out: protocol failure -> finishes fast with wrong numbers (loud).
__device__ __forceinline__ void wait_cnt(const unsigned* p, unsigned need, int& budget) {
  for (;;) {
    unsigned v = __hip_atomic_load(p, __ATOMIC_RELAXED, __HIP_MEMORY_SCOPE_AGENT);
    if (v >= need) break;
    if (--budget < 0) break;
    __builtin_amdgcn_s_sleep(1);
  }
  asm volatile("" ::: "memory");   // compiler acquire: keep h loads after the poll
}

extern "C" __global__ void __launch_bounds__(NTHREADS, 1)
lstm_persist(const float* __restrict__ x,  const float* __restrict__ W0,
             const float* __restrict__ b0, const float* __restrict__ W1,
             const float* __restrict__ b1, const float* __restrict__ Wfc,
             const float* __restrict__ bfc, float* __restrict__ out,
             unsigned char* __restrict__ ws, int Wn, int wmask, int fimask, int slack)
{
  extern __shared__ char lds[];
  f16*   w0l     = (f16*)(lds + LDS_W0_OFF);
  f16*   w1l     = (f16*)(lds + LDS_W1_OFF);
  float* stgbase = (float*)(lds + LDS_STG_OFF);

  const int tid   = threadIdx.x;
  const int wg    = blockIdx.x & (WGS - 1);
  const int cl    = blockIdx.x / WGS;
  const int wave  = tid >> 6;
  const int lane  = tid & 63;
  const int hbase = wg * 8;

  // ---- one-time: gather + transpose this WG's weight columns into LDS (fp16) ----
  {
    const int nl = tid & 31;
    const int wtile = nl >> 4, wi = nl & 15, g = wi >> 2, jj = wi & 3;
    const int col = g * HID + hbase + wtile * 4 + jj;
    for (int k = tid >> 5; k < K0; k += 8)
      w0l[nl * KP0 + k] = (f16)W0[(size_t)k * GATES + col];
    for (int k = tid >> 5; k < K1; k += 8)
      w1l[nl * KP1 + k] = (f16)W1[(size_t)k * GATES + col];
  }
  __syncthreads();   // last block-wide sync; waves run independently below

  // ---- per-wave constants ----
  const int layer = wave >> 1;
  const int tile  = wave & 1;
  const int cb    = hbase + tile * 4;
  const int erow  = lane >> 2;
  const int ehc   = lane & 3;
  const int hcol  = cb + ehc;
  const float* bsrc = layer ? b1 : b0;
  const float bg0 = bsrc[0 * HID + hcol];
  const float bg1 = bsrc[1 * HID + hcol];
  const float bg2 = bsrc[2 * HID + hcol];
  const float bg3 = bsrc[3 * HID + hcol];
  float cstate = 0.f;
  float* stg = stgbase + wave * (16 * 17);

  const int fm  = lane & 15;
  const int q8  = (lane >> 4) * 8;
  const int brow = cl * BPC + fm;

  unsigned char* hby = ws + WS_FLAG_BYTES;
  unsigned int* f0cnt = (unsigned int*)(ws + (size_t)cl * 8192);
  unsigned int* f1cnt = (unsigned int*)(ws + (size_t)cl * 8192 + 2048);
  int budget = 1 << 20;

  auto slotp = [&](int lyr, int t, int hl) -> f16* {
    return (f16*)(hby + ((size_t)((cl * 2 + lyr) * Wn + (t & wmask)) << 15) + (hl << 14));
  };

  // epilogue: acc -> gates -> (h, cstate) -> versioned slot store
  auto do_epilogue = [&](f32x4 acc, int t) {
    #pragma unroll
    for (int r = 0; r < 4; ++r)
      stg[((lane >> 4) * 4 + r) * 17 + fm] = acc[r];
    float iv = stg[erow * 17 + 0 + ehc]  + bg0;
    float fv = stg[erow * 17 + 4 + ehc]  + bg1;
    float gv = stg[erow * 17 + 8 + ehc]  + bg2;
    float ov = stg[erow * 17 + 12 + ehc] + bg3;
    float ig = sigf(iv), fg = sigf(fv), gg = tanh_f(gv), og = sigf(ov);
    cstate = fg * cstate + ig * gg;
    float h = og * tanh_f(cstate);

    const int src0 = fm * 4 + ((lane >> 4) & 1) * 2;
    float ha = __shfl(h, src0, 64);
    float hb = __shfl(h, src0 + 1, 64);
    if (lane < 32) {
      const int wrow = lane & 15, wpair = lane >> 4;
      f16* phi = slotp(layer, t, 0);
      f16* plo = slotp(layer, t, 1);
      f16 hah = (f16)ha; f16 hal = (f16)(ha - (float)hah);
      f16 hbh = (f16)hb; f16 hbl = (f16)(hb - (float)hbh);
      unsigned int hw = (unsigned int)__builtin_bit_cast(unsigned short, hah) |
                        ((unsigned int)__builtin_bit_cast(unsigned short, hbh) << 16);
      unsigned int lw = (unsigned int)__builtin_bit_cast(unsigned short, hal) |
                        ((unsigned int)__builtin_bit_cast(unsigned short, hbl) << 16);
      const int coff = wrow * HID + cb + wpair * 2;
      __hip_atomic_store((unsigned int*)(phi + coff), hw, __ATOMIC_RELAXED, __HIP_MEMORY_SCOPE_AGENT);
      __hip_atomic_store((unsigned int*)(plo + coff), lw, __ATOMIC_RELAXED, __HIP_MEMORY_SCOPE_AGENT);
    }
    RELEASE_DRAIN();   // h stores ack'd at coherence point before the count bump
  };

  if (layer == 0) {
    for (int t = 0; t < S_LEN; ++t) {
      if (t && (t & fimask) == 0)
        __builtin_amdgcn_fence(__ATOMIC_ACQUIRE, "agent");  // slot-reuse invalidate (every W/2)
      f32x4 acc = {0.f, 0.f, 0.f, 0.f};
      // x part first: independent of the recurrence
      const float* xr = x + ((size_t)brow * S_LEN + t) * IN_D + q8;
      #pragma unroll
      for (int kb = 0; kb < 2; ++kb) {
        f32x4 xa = *(const f32x4*)(xr + kb * 32);
        f32x4 xb = *(const f32x4*)(xr + kb * 32 + 4);
        f16x8 a = { (f16)xa[0], (f16)xa[1], (f16)xa[2], (f16)xa[3],
                    (f16)xb[0], (f16)xb[1], (f16)xb[2], (f16)xb[3] };
        f16x8 bf = *(const f16x8*)(w0l + (tile * 16 + fm) * KP0 + kb * 32 + q8);
        acc = MFMA(a, bf, acc);
      }
      if (t) {
        wait_cnt(f0cnt + (t - 1), NPROD, budget);               // h0(t-1) ready
        if (t > slack) wait_cnt(f1cnt + (t - slack - 1), NPROD, budget);  // window back-pressure
        const f16* hpi = slotp(0, t - 1, 0) + fm * HID + q8;
        const f16* hpl = slotp(0, t - 1, 1) + fm * HID + q8;
        // (a) batch all 32 loads -> one latency exposure
        f16x8 ah[16], al[16];
        #pragma unroll
        for (int kb = 0; kb < 16; ++kb) {
          ah[kb] = *(const f16x8*)(hpi + kb * 32);
          al[kb] = *(const f16x8*)(hpl + kb * 32);
        }
        // (b) independent hi/lo chains (depth 16 each)
        f32x4 acl = {0.f, 0.f, 0.f, 0.f};
        #pragma unroll
        for (int kb = 0; kb < 16; ++kb) {
          f16x8 bf = *(const f16x8*)(w0l + (tile * 16 + fm) * KP0 + IN_D + kb * 32 + q8);
          acc = MFMA(ah[kb], bf, acc);
          acl = MFMA(al[kb], bf, acl);
        }
        acc = acc + acl;
      }
      do_epilogue(acc, t);
      if (lane == 0) atomicAdd(f0cnt + t, 1u);                  // device-scope (G12)
    }
  } else {
    for (int t = 0; t < S_LEN; ++t) {
      if (t && (t & fimask) == 0)
        __builtin_amdgcn_fence(__ATOMIC_ACQUIRE, "agent");
      f32x4 acc = {0.f, 0.f, 0.f, 0.f};
      f32x4 acl = {0.f, 0.f, 0.f, 0.f};
      wait_cnt(f0cnt + t, NPROD, budget);                       // h0(t) ready
      {
        const f16* h0i = slotp(0, t, 0) + fm * HID + q8;
        const f16* h0l = slotp(0, t, 1) + fm * HID + q8;
        f16x8 ah[16], al[16];
        #pragma unroll
        for (int kb = 0; kb < 16; ++kb) {
          ah[kb] = *(const f16x8*)(h0i + kb * 32);
          al[kb] = *(const f16x8*)(h0l + kb * 32);
        }
        #pragma unroll
        for (int kb = 0; kb < 16; ++kb) {
          f16x8 bf = *(const f16x8*)(w1l + (tile * 16 + fm) * KP1 + kb * 32 + q8);
          acc = MFMA(ah[kb], bf, acc);
          acl = MFMA(al[kb], bf, acl);
        }
      }
      if (t) {
        wait_cnt(f1cnt + (t - 1), NPROD, budget);               // h1(t-1) ready (peers)
        const f16* h1i = slotp(1, t - 1, 0) + fm * HID + q8;
        const f16* h1l = slotp(1, t - 1, 1) + fm * HID + q8;
        f16x8 ah[16], al[16];
        #pragma unroll
        for (int kb = 0; kb < 16; ++kb) {
          ah[kb] = *(const f16x8*)(h1i + kb * 32);
          al[kb] = *(const f16x8*)(h1l + kb * 32);
        }
        #pragma unroll
        for (int kb = 0; kb < 16; ++kb) {
          f16x8 bf = *(const f16x8*)(w1l + (tile * 16 + fm) * KP1 + HID + kb * 32 + q8);
          acc = MFMA(ah[kb], bf, acc);
          acl = MFMA(al[kb], bf, acl);
        }
      }
      acc = acc + acl;
      do_epilogue(acc, t);
      if (lane == 0) atomicAdd(f1cnt + t, 1u);
    }
  }

  // ---- output head: WG0 of each cluster reads h1(511) ----
  if (wg == 0) {
    wait_cnt(f1cnt + (S_LEN - 1), NPROD, budget);
    __builtin_amdgcn_fence(__ATOMIC_ACQUIRE, "agent");
    const f16* h1i = slotp(1, S_LEN - 1, 0);
    const f16* h1l = slotp(1, S_LEN - 1, 1);
    #pragma unroll
    for (int rr = 0; rr < 4; ++rr) {
      const int r = wave * 4 + rr;
      float sum = 0.f;
      for (int k = lane; k < HID; k += 64) {
        float hv = (float)h1i[r * HID + k] + (float)h1l[r * HID + k];
        sum += hv * Wfc[k];
      }
      #pragma unroll
      for (int off = 32; off > 0; off >>= 1)
        sum += __shfl_down(sum, off, 64);
      if (lane == 0) out[cl * BPC + r] = sum + bfc[0];
    }
  }
}

extern "C" void kernel_launch(void* const* d_in, const int* in_sizes, int n_in,
                              void* d_out, int out_size, void* d_ws, size_t ws_size,
                              hipStream_t stream) {
  const float* x   = (const float*)d_in[0];
  const float* W0  = (const float*)d_in[1];
  const float* b0  = (const float*)d_in[2];
  const float* W1  = (const float*)d_in[3];
  const float* b1  = (const float*)d_in[4];
  const float* Wfc = (const float*)d_in[5];
  const float* bfc = (const float*)d_in[6];
  float* out = (float*)d_out;
  unsigned char* ws = (unsigned char*)d_ws;

  (void)in_sizes; (void)n_in; (void)out_size;

  // window size from available workspace (cap 64 slots = 16.8 MB)
  int Wn = 2;
  while (Wn < 64 &&
         WS_FLAG_BYTES + (size_t)(Wn * 2) * (CLUSTERS * 2 * SLOT_BYTES) <= ws_size)
    Wn *= 2;
  int wmask  = Wn - 1;
  int fimask = (Wn >= 4) ? (Wn / 2 - 1) : 0;  // acquire-fence every Wn/2 steps
  int slack  = Wn - 2;

  hipFuncSetAttribute((const void*)lstm_persist,
                      hipFuncAttributeMaxDynamicSharedMemorySize, LDS_TOTAL);

  // zero the flag/counter region each call (h slots are written before read)
  hipMemsetAsync(ws, 0, WS_FLAG_BYTES, stream);

  void* args[] = { &x, &W0, &b0, &W1, &b1, &Wfc, &bfc, &out, &ws,
                   &Wn, &wmask, &fimask, &slack };
  hipLaunchCooperativeKernel((void*)lstm_persist, dim3(NBLOCKS), dim3(NTHREADS),
                             args, LDS_TOTAL, stream);
}